// Round 11
// baseline (228.702 us; speedup 1.0000x reference)
//
#include <hip/hip_runtime.h>

#define N_NODES 50000
#define N_EDGES 800000
#define D 64
#define NSLICE 8
#define SLICE_N ((N_NODES + NSLICE - 1) / NSLICE)   // 6250
#define BCAP 64        // bucket capacity; deg ~ Poisson(16), P(deg>=64) ~ 1e-19

// float -> bf16 (round-to-nearest-even), as raw ushort
__device__ __forceinline__ unsigned short f2bf(float f) {
    unsigned int u = __builtin_bit_cast(unsigned int, f);
    u += 0x7fffu + ((u >> 16) & 1u);
    return (unsigned short)(u >> 16);
}
__device__ __forceinline__ float bflo(unsigned int u) {
    return __builtin_bit_cast(float, u << 16);
}
__device__ __forceinline__ float bfhi(unsigned int u) {
    return __builtin_bit_cast(float, u & 0xffff0000u);
}

// ---------------- bucketed CSR fill (XCD-partitioned by dst slice) ----------------
__global__ __launch_bounds__(256) void k_fill2(const int* __restrict__ src,
                                               const int* __restrict__ dst,
                                               int* __restrict__ cnt,
                                               int* __restrict__ csr) {
    int slice = blockIdx.x & (NSLICE - 1);
    int lo = slice * SLICE_N, hi = lo + SLICE_N;
    int gblk = blockIdx.x >> 3, nblk = gridDim.x >> 3;
    for (int e = gblk * blockDim.x + threadIdx.x; e < N_EDGES; e += nblk * blockDim.x) {
        int d = dst[e];
        if (d >= lo && d < hi) {
            int p = atomicAdd(&cnt[d], 1);
            csr[(d << 6) + p] = src[e];
        }
    }
}

// ---------------- layer-0 transform: yS = x@Ws + b (fp32), yN = x@Wn (bf16) ----------------
// Unchanged from R10. zero_cnt folds the cnt memset into this dispatch.
__global__ __launch_bounds__(256, 4) void k_xform(const float* __restrict__ h,
        const float* __restrict__ Ws, const float* __restrict__ Wn,
        const float* __restrict__ b,
        float* __restrict__ yS, unsigned short* __restrict__ yN,
        int* __restrict__ cnt, int zero_cnt) {
    if (zero_cnt && blockIdx.x < 196) {
        int i = blockIdx.x * 256 + threadIdx.x;
        if (i < N_NODES) cnt[i] = 0;
    }
    int lane = threadIdx.x & 63;
    int gwave = __builtin_amdgcn_readfirstlane((blockIdx.x * blockDim.x + threadIdx.x) >> 6);
    int nwaves = (gridDim.x * blockDim.x) >> 6;

    int mat = gwave & 1;
    const float* W = mat ? Wn : Ws;

    float w[D];
#pragma unroll
    for (int k = 0; k < D; ++k) w[k] = W[k * D + lane];
    float bj = mat ? 0.f : b[lane];

    const int ngroups = (N_NODES + 3) / 4;   // 12500, exact
    for (int g = gwave >> 1; g < ngroups; g += (nwaves >> 1)) {
        const float* x0 = h + (size_t)(g * 4) * D;
        float a0 = bj, a1 = bj, a2 = bj, a3 = bj;
#pragma unroll
        for (int kq = 0; kq < 16; ++kq) {
            float4 v0 = *(const float4*)(x0 + 0 * D + kq * 4);
            float4 v1 = *(const float4*)(x0 + 1 * D + kq * 4);
            float4 v2 = *(const float4*)(x0 + 2 * D + kq * 4);
            float4 v3 = *(const float4*)(x0 + 3 * D + kq * 4);
            a0 = fmaf(v0.x, w[kq * 4 + 0], a0);
            a1 = fmaf(v1.x, w[kq * 4 + 0], a1);
            a2 = fmaf(v2.x, w[kq * 4 + 0], a2);
            a3 = fmaf(v3.x, w[kq * 4 + 0], a3);
            a0 = fmaf(v0.y, w[kq * 4 + 1], a0);
            a1 = fmaf(v1.y, w[kq * 4 + 1], a1);
            a2 = fmaf(v2.y, w[kq * 4 + 1], a2);
            a3 = fmaf(v3.y, w[kq * 4 + 1], a3);
            a0 = fmaf(v0.z, w[kq * 4 + 2], a0);
            a1 = fmaf(v1.z, w[kq * 4 + 2], a1);
            a2 = fmaf(v2.z, w[kq * 4 + 2], a2);
            a3 = fmaf(v3.z, w[kq * 4 + 2], a3);
            a0 = fmaf(v0.w, w[kq * 4 + 3], a0);
            a1 = fmaf(v1.w, w[kq * 4 + 3], a1);
            a2 = fmaf(v2.w, w[kq * 4 + 3], a2);
            a3 = fmaf(v3.w, w[kq * 4 + 3], a3);
        }
        size_t base = (size_t)(g * 4) * D + lane;
        if (mat) {
            yN[base + 0 * D] = f2bf(a0);
            yN[base + 1 * D] = f2bf(a1);
            yN[base + 2 * D] = f2bf(a2);
            yN[base + 3 * D] = f2bf(a3);
        } else {
            yS[base + 0 * D] = a0;
            yS[base + 1 * D] = a1;
            yS[base + 2 * D] = a2;
            yS[base + 3 * D] = a3;
        }
    }
}

// gather core (R10's uint4 deg-adaptive rounds) producing the relu'd h value
// for feature f = fq*8+q of `node`. Defined as a macro-free inline.
__device__ __forceinline__ float gather_h(const char* __restrict__ yN,
        const float* __restrict__ yS, const int* __restrict__ cnt,
        const int* __restrict__ csr, int node, int q, int fq, int relu) {
    int deg = cnt[node];
    const int* bucket = csr + (node << 6);
    unsigned foff = (unsigned)fq * 16u;

    float s0 = 0.f, s1 = 0.f, s2 = 0.f, s3 = 0.f;
    float s4 = 0.f, s5 = 0.f, s6 = 0.f, s7 = 0.f;

#define ROUND16(E0)                                                         \
    {                                                                       \
        int i0 = (E0) + q, i1 = i0 + 8;                                     \
        int b0 = bucket[i0], b1 = bucket[i1];                               \
        unsigned a0 = (i0 < deg) ? ((unsigned)b0 << 7) : 0u;                \
        unsigned a1 = (i1 < deg) ? ((unsigned)b1 << 7) : 0u;                \
        float m0 = (i0 < deg) ? 1.f : 0.f;                                  \
        float m1 = (i1 < deg) ? 1.f : 0.f;                                  \
        uint4 u0 = *(const uint4*)(yN + a0 + foff);                         \
        uint4 u1 = *(const uint4*)(yN + a1 + foff);                         \
        s0 = fmaf(m0, bflo(u0.x), s0); s0 = fmaf(m1, bflo(u1.x), s0);       \
        s1 = fmaf(m0, bfhi(u0.x), s1); s1 = fmaf(m1, bfhi(u1.x), s1);       \
        s2 = fmaf(m0, bflo(u0.y), s2); s2 = fmaf(m1, bflo(u1.y), s2);       \
        s3 = fmaf(m0, bfhi(u0.y), s3); s3 = fmaf(m1, bfhi(u1.y), s3);       \
        s4 = fmaf(m0, bflo(u0.z), s4); s4 = fmaf(m1, bflo(u1.z), s4);       \
        s5 = fmaf(m0, bfhi(u0.z), s5); s5 = fmaf(m1, bfhi(u1.z), s5);       \
        s6 = fmaf(m0, bflo(u0.w), s6); s6 = fmaf(m1, bflo(u1.w), s6);       \
        s7 = fmaf(m0, bfhi(u0.w), s7); s7 = fmaf(m1, bfhi(u1.w), s7);       \
    }

    ROUND16(0)
    if (deg > 16) ROUND16(16)
    if (deg > 32) {
        ROUND16(32)
        if (deg > 48) ROUND16(48)
    }
#undef ROUND16

    s0 += __shfl_xor(s0, 8, 64); s0 += __shfl_xor(s0, 16, 64); s0 += __shfl_xor(s0, 32, 64);
    s1 += __shfl_xor(s1, 8, 64); s1 += __shfl_xor(s1, 16, 64); s1 += __shfl_xor(s1, 32, 64);
    s2 += __shfl_xor(s2, 8, 64); s2 += __shfl_xor(s2, 16, 64); s2 += __shfl_xor(s2, 32, 64);
    s3 += __shfl_xor(s3, 8, 64); s3 += __shfl_xor(s3, 16, 64); s3 += __shfl_xor(s3, 32, 64);
    s4 += __shfl_xor(s4, 8, 64); s4 += __shfl_xor(s4, 16, 64); s4 += __shfl_xor(s4, 32, 64);
    s5 += __shfl_xor(s5, 8, 64); s5 += __shfl_xor(s5, 16, 64); s5 += __shfl_xor(s5, 32, 64);
    s6 += __shfl_xor(s6, 8, 64); s6 += __shfl_xor(s6, 16, 64); s6 += __shfl_xor(s6, 32, 64);
    s7 += __shfl_xor(s7, 8, 64); s7 += __shfl_xor(s7, 16, 64); s7 += __shfl_xor(s7, 32, 64);

    float sv = (q == 0) ? s0 : (q == 1) ? s1 : (q == 2) ? s2 : (q == 3) ? s3
             : (q == 4) ? s4 : (q == 5) ? s5 : (q == 6) ? s6 : s7;
    int f = fq * 8 + q;
    float self = yS[(size_t)node * D + f];
    float inv = 1.0f / fmaxf((float)deg, 1.0f);
    float acc = self + sv * inv;
    if (relu) acc = fmaxf(acc, 0.f);
    return acc;
}

// ---------------- FUSED: layer-0 aggregate + layer-1 transform ----------------
// Each wave handles 8 nodes. Per node: gather h-row (one feature per lane,
// f = fq*8+q), round-trip through a per-wave 256 B LDS buffer (wave-synchronous
// exchange; lgkmcnt ordering is compiler-inserted), then yS2 = h@Ws1 + b1 and
// yN2 = bf16(h@Wn1) with both weight columns register-resident (2x64 VGPR,
// amortized over 8 nodes; 2x16 KB weights are L1-resident). h never touches
// global memory; saves the xform1 dispatch + 25.6 MB round-trip. Matmul k-order
// matches k_xform (single acc, k ascending) -> identical rounding.
__global__ __launch_bounds__(256) void k_aggx(const char* __restrict__ yN,
        const float* __restrict__ yS,
        const int* __restrict__ cnt, const int* __restrict__ csr,
        const float* __restrict__ Ws1, const float* __restrict__ Wn1,
        const float* __restrict__ b1,
        float* __restrict__ yS2, unsigned short* __restrict__ yN2) {
    __shared__ float hrow[4][D];
    int lane = threadIdx.x & 63;
    int wib  = threadIdx.x >> 6;                  // wave in block 0..3
    int gwave = __builtin_amdgcn_readfirstlane(blockIdx.x * 4 + wib);
    int q = lane >> 3;          // edge sub-slot 0..7
    int fq = lane & 7;          // uint4 slot within the 128 B row
    int f = fq * 8 + q;         // feature produced by this lane in gather phase

    float wsc[D], wnc[D];
#pragma unroll
    for (int k = 0; k < D; ++k) {
        wsc[k] = Ws1[k * D + lane];
        wnc[k] = Wn1[k * D + lane];
    }
    float bj = b1[lane];
    float* myrow = hrow[wib];

    int node0 = gwave * 8;
#pragma unroll 1
    for (int it = 0; it < 8; ++it) {
        int node = node0 + it;
        if (node >= N_NODES) break;               // wave-uniform

        float h = gather_h(yN, yS, cnt, csr, node, q, fq, 1);
        myrow[f] = h;                             // wave-sync LDS exchange

        float a0 = bj, a1 = 0.f;
#pragma unroll
        for (int kq = 0; kq < 16; ++kq) {
            float4 hk = *(const float4*)(&myrow[kq * 4]);   // uniform addr: LDS broadcast
            a0 = fmaf(hk.x, wsc[kq * 4 + 0], a0);
            a1 = fmaf(hk.x, wnc[kq * 4 + 0], a1);
            a0 = fmaf(hk.y, wsc[kq * 4 + 1], a0);
            a1 = fmaf(hk.y, wnc[kq * 4 + 1], a1);
            a0 = fmaf(hk.z, wsc[kq * 4 + 2], a0);
            a1 = fmaf(hk.z, wnc[kq * 4 + 2], a1);
            a0 = fmaf(hk.w, wsc[kq * 4 + 3], a0);
            a1 = fmaf(hk.w, wnc[kq * 4 + 3], a1);
        }
        size_t base = (size_t)node * D + lane;
        yS2[base] = a0;
        yN2[base] = f2bf(a1);
    }
}

// ---------------- final mean-aggregate + self (layer 1, no relu) ----------------
__global__ __launch_bounds__(256) void k_aggf(const char* __restrict__ yN,
        const float* __restrict__ yS,
        const int* __restrict__ cnt, const int* __restrict__ csr,
        float* __restrict__ out, int relu) {
    int node = __builtin_amdgcn_readfirstlane((blockIdx.x * blockDim.x + threadIdx.x) >> 6);
    int lane = threadIdx.x & 63;
    int q = lane >> 3;
    int fq = lane & 7;
    float acc = gather_h(yN, yS, cnt, csr, node, q, fq, relu);
    out[(size_t)node * D + fq * 8 + q] = acc;
}

extern "C" void kernel_launch(void* const* d_in, const int* in_sizes, int n_in,
                              void* d_out, int out_size, void* d_ws, size_t ws_size,
                              hipStream_t stream) {
    const float* x   = (const float*)d_in[0];
    const int*   src = (const int*)d_in[1];
    const int*   dst = (const int*)d_in[2];
    const float* Ws0 = (const float*)d_in[3];
    const float* Wn0 = (const float*)d_in[4];
    const float* b0  = (const float*)d_in[5];
    const float* Ws1 = (const float*)d_in[6];
    const float* Wn1 = (const float*)d_in[7];
    const float* b1  = (const float*)d_in[8];
    float* out = (float*)d_out;

    // workspace layout
    char* p = (char*)d_ws;
    float*          yS  = (float*)p;          p += (size_t)N_NODES * D * sizeof(float);
    unsigned short* yN  = (unsigned short*)p; p += (size_t)N_NODES * D * sizeof(unsigned short);
    float*          yS2 = (float*)p;          p += (size_t)N_NODES * D * sizeof(float);
    unsigned short* yN2 = (unsigned short*)p; p += (size_t)N_NODES * D * sizeof(unsigned short);
    int* cnt = (int*)p;                       p += (size_t)N_NODES * sizeof(int);
    int* csr = (int*)p;                       p += (size_t)N_NODES * BCAP * sizeof(int);

    const int aggBlocks  = (N_NODES + 3) / 4;        // 12500: wave per node
    const int aggxBlocks = (N_NODES + 31) / 32;      // 1563: wave per 8 nodes

    // K1: layer-0 transform (+ cnt zero)   K2: CSR fill
    k_xform<<<1024, 256, 0, stream>>>(x, Ws0, Wn0, b0, yS, yN, cnt, 1);
    k_fill2<<<1024, 256, 0, stream>>>(src, dst, cnt, csr);
    // K3: fused layer-0 aggregate + layer-1 transform (h stays on-chip)
    k_aggx<<<aggxBlocks, 256, 0, stream>>>((const char*)yN, yS, cnt, csr,
                                           Ws1, Wn1, b1, yS2, yN2);
    // K4: final aggregate -> d_out
    k_aggf<<<aggBlocks, 256, 0, stream>>>((const char*)yN2, yS2, cnt, csr, out, 0);
}

// Round 12
// 189.530 us; speedup vs baseline: 1.2067x; 1.2067x over previous
//
#include <hip/hip_runtime.h>

#define N_NODES 50000
#define N_EDGES 800000
#define D 64
#define NSLICE 8
#define SLICE_N ((N_NODES + NSLICE - 1) / NSLICE)   // 6250
#define BCAP 64        // bucket capacity; deg ~ Poisson(16), P(deg>=64) ~ 1e-19

// float -> bf16 (round-to-nearest-even), as raw ushort
__device__ __forceinline__ unsigned short f2bf(float f) {
    unsigned int u = __builtin_bit_cast(unsigned int, f);
    u += 0x7fffu + ((u >> 16) & 1u);
    return (unsigned short)(u >> 16);
}
__device__ __forceinline__ float bflo(unsigned int u) {
    return __builtin_bit_cast(float, u << 16);
}
__device__ __forceinline__ float bfhi(unsigned int u) {
    return __builtin_bit_cast(float, u & 0xffff0000u);
}

// ---------------- shared transform body: yS = h@Ws + b (fp32), yN = h@Wn (bf16) ----
// Wave-specialized (even gwave -> Ws/yS, odd -> Wn/yN). Lane = output column,
// W column held in 64 VGPRs; h rows read as wave-uniform float4.
__device__ __forceinline__ void xform_body(const float* __restrict__ h,
        const float* __restrict__ Ws, const float* __restrict__ Wn,
        const float* __restrict__ b,
        float* __restrict__ yS, unsigned short* __restrict__ yN,
        int gwave, int nwaves, int lane) {
    int mat = gwave & 1;
    const float* W = mat ? Wn : Ws;

    float w[D];
#pragma unroll
    for (int k = 0; k < D; ++k) w[k] = W[k * D + lane];
    float bj = mat ? 0.f : b[lane];

    const int ngroups = (N_NODES + 3) / 4;   // 12500, exact
    for (int g = gwave >> 1; g < ngroups; g += (nwaves >> 1)) {
        const float* x0 = h + (size_t)(g * 4) * D;
        float a0 = bj, a1 = bj, a2 = bj, a3 = bj;
#pragma unroll
        for (int kq = 0; kq < 16; ++kq) {
            float4 v0 = *(const float4*)(x0 + 0 * D + kq * 4);
            float4 v1 = *(const float4*)(x0 + 1 * D + kq * 4);
            float4 v2 = *(const float4*)(x0 + 2 * D + kq * 4);
            float4 v3 = *(const float4*)(x0 + 3 * D + kq * 4);
            a0 = fmaf(v0.x, w[kq * 4 + 0], a0);
            a1 = fmaf(v1.x, w[kq * 4 + 0], a1);
            a2 = fmaf(v2.x, w[kq * 4 + 0], a2);
            a3 = fmaf(v3.x, w[kq * 4 + 0], a3);
            a0 = fmaf(v0.y, w[kq * 4 + 1], a0);
            a1 = fmaf(v1.y, w[kq * 4 + 1], a1);
            a2 = fmaf(v2.y, w[kq * 4 + 1], a2);
            a3 = fmaf(v3.y, w[kq * 4 + 1], a3);
            a0 = fmaf(v0.z, w[kq * 4 + 2], a0);
            a1 = fmaf(v1.z, w[kq * 4 + 2], a1);
            a2 = fmaf(v2.z, w[kq * 4 + 2], a2);
            a3 = fmaf(v3.z, w[kq * 4 + 2], a3);
            a0 = fmaf(v0.w, w[kq * 4 + 3], a0);
            a1 = fmaf(v1.w, w[kq * 4 + 3], a1);
            a2 = fmaf(v2.w, w[kq * 4 + 3], a2);
            a3 = fmaf(v3.w, w[kq * 4 + 3], a3);
        }
        size_t base = (size_t)(g * 4) * D + lane;
        if (mat) {
            yN[base + 0 * D] = f2bf(a0);
            yN[base + 1 * D] = f2bf(a1);
            yN[base + 2 * D] = f2bf(a2);
            yN[base + 3 * D] = f2bf(a3);
        } else {
            yS[base + 0 * D] = a0;
            yS[base + 1 * D] = a1;
            yS[base + 2 * D] = a2;
            yS[base + 3 * D] = a3;
        }
    }
}

// ---------------- FUSED stage 1: layer-0 transform (even blocks) ∥ CSR fill (odd) ----
// xform0 (VALU-bound) and fill (atomic/memory-bound) are independent; parity
// role split co-schedules them on every CU (MFMA/VALU + memory waves overlap —
// m114). cnt is pre-zeroed by a stream-ordered memset, so there is no
// intra-kernel dependency between roles. Fill keeps the dst-slice XCD
// partition (R2 showed 17x write amplification without it).
__global__ __launch_bounds__(256) void k_pre(const float* __restrict__ x,
        const float* __restrict__ Ws0, const float* __restrict__ Wn0,
        const float* __restrict__ b0,
        float* __restrict__ yS, unsigned short* __restrict__ yN,
        const int* __restrict__ src, const int* __restrict__ dst,
        int* __restrict__ cnt, int* __restrict__ csr) {
    int role = blockIdx.x & 1;
    int sub  = blockIdx.x >> 1;          // 0..1023 within the role
    if (role == 0) {
        int lane = threadIdx.x & 63;
        int gwave = __builtin_amdgcn_readfirstlane(sub * 4 + (int)(threadIdx.x >> 6));
        xform_body(x, Ws0, Wn0, b0, yS, yN, gwave, 4096, lane);
    } else {
        int slice = sub & (NSLICE - 1);
        int lo = slice * SLICE_N, hi = lo + SLICE_N;
        int gblk = sub >> 3, nblk = 1024 >> 3;   // 128 blocks per slice
        for (int e = gblk * 256 + (int)threadIdx.x; e < N_EDGES; e += nblk * 256) {
            int d = dst[e];
            if (d >= lo && d < hi) {
                int p = atomicAdd(&cnt[d], 1);
                csr[(d << 6) + p] = src[e];
            }
        }
    }
}

// ---------------- layer-1 transform (standalone, R10 body) ----------------
__global__ __launch_bounds__(256, 4) void k_xform(const float* __restrict__ h,
        const float* __restrict__ Ws, const float* __restrict__ Wn,
        const float* __restrict__ b,
        float* __restrict__ yS, unsigned short* __restrict__ yN) {
    int lane = threadIdx.x & 63;
    int gwave = __builtin_amdgcn_readfirstlane((blockIdx.x * blockDim.x + threadIdx.x) >> 6);
    int nwaves = (gridDim.x * blockDim.x) >> 6;
    xform_body(h, Ws, Wn, b, yS, yN, gwave, nwaves, lane);
}

// ---------------- fused mean-aggregate + self + epilogue (R10, unchanged) ----------
// uint4 gathers (1 KB/wave-instr), deg-adaptive 16-edge rounds, masked slots
// read row 0 and contribute *0.0f (exact). 8 accumulators, 3 xor-shuffles
// each; lane (q,fq) writes feature fq*8+q.
__global__ __launch_bounds__(256) void k_aggf(const char* __restrict__ yN,
        const float* __restrict__ yS,
        const int* __restrict__ cnt, const int* __restrict__ csr,
        float* __restrict__ out, int relu) {
    int node = __builtin_amdgcn_readfirstlane((blockIdx.x * blockDim.x + threadIdx.x) >> 6);
    int lane = threadIdx.x & 63;
    int q = lane >> 3;          // edge sub-slot 0..7
    int fq = lane & 7;          // uint4 slot within the 128 B row
    int deg = cnt[node];
    const int* bucket = csr + (node << 6);
    unsigned foff = (unsigned)fq * 16u;

    float s0 = 0.f, s1 = 0.f, s2 = 0.f, s3 = 0.f;
    float s4 = 0.f, s5 = 0.f, s6 = 0.f, s7 = 0.f;

#define ROUND16(E0)                                                         \
    {                                                                       \
        int i0 = (E0) + q, i1 = i0 + 8;                                     \
        int b0 = bucket[i0], b1 = bucket[i1];                               \
        unsigned a0 = (i0 < deg) ? ((unsigned)b0 << 7) : 0u;                \
        unsigned a1 = (i1 < deg) ? ((unsigned)b1 << 7) : 0u;                \
        float m0 = (i0 < deg) ? 1.f : 0.f;                                  \
        float m1 = (i1 < deg) ? 1.f : 0.f;                                  \
        uint4 u0 = *(const uint4*)(yN + a0 + foff);                         \
        uint4 u1 = *(const uint4*)(yN + a1 + foff);                         \
        s0 = fmaf(m0, bflo(u0.x), s0); s0 = fmaf(m1, bflo(u1.x), s0);       \
        s1 = fmaf(m0, bfhi(u0.x), s1); s1 = fmaf(m1, bfhi(u1.x), s1);       \
        s2 = fmaf(m0, bflo(u0.y), s2); s2 = fmaf(m1, bflo(u1.y), s2);       \
        s3 = fmaf(m0, bfhi(u0.y), s3); s3 = fmaf(m1, bfhi(u1.y), s3);       \
        s4 = fmaf(m0, bflo(u0.z), s4); s4 = fmaf(m1, bflo(u1.z), s4);       \
        s5 = fmaf(m0, bfhi(u0.z), s5); s5 = fmaf(m1, bfhi(u1.z), s5);       \
        s6 = fmaf(m0, bflo(u0.w), s6); s6 = fmaf(m1, bflo(u1.w), s6);       \
        s7 = fmaf(m0, bfhi(u0.w), s7); s7 = fmaf(m1, bfhi(u1.w), s7);       \
    }

    ROUND16(0)                          // deg<=16: 53% of nodes stop here
    if (deg > 16) ROUND16(16)           // ~44%
    if (deg > 32) {                     // ~3%
        ROUND16(32)
        if (deg > 48) ROUND16(48)       // ~1e-4
    }
#undef ROUND16

    s0 += __shfl_xor(s0, 8, 64); s0 += __shfl_xor(s0, 16, 64); s0 += __shfl_xor(s0, 32, 64);
    s1 += __shfl_xor(s1, 8, 64); s1 += __shfl_xor(s1, 16, 64); s1 += __shfl_xor(s1, 32, 64);
    s2 += __shfl_xor(s2, 8, 64); s2 += __shfl_xor(s2, 16, 64); s2 += __shfl_xor(s2, 32, 64);
    s3 += __shfl_xor(s3, 8, 64); s3 += __shfl_xor(s3, 16, 64); s3 += __shfl_xor(s3, 32, 64);
    s4 += __shfl_xor(s4, 8, 64); s4 += __shfl_xor(s4, 16, 64); s4 += __shfl_xor(s4, 32, 64);
    s5 += __shfl_xor(s5, 8, 64); s5 += __shfl_xor(s5, 16, 64); s5 += __shfl_xor(s5, 32, 64);
    s6 += __shfl_xor(s6, 8, 64); s6 += __shfl_xor(s6, 16, 64); s6 += __shfl_xor(s6, 32, 64);
    s7 += __shfl_xor(s7, 8, 64); s7 += __shfl_xor(s7, 16, 64); s7 += __shfl_xor(s7, 32, 64);

    float sv = (q == 0) ? s0 : (q == 1) ? s1 : (q == 2) ? s2 : (q == 3) ? s3
             : (q == 4) ? s4 : (q == 5) ? s5 : (q == 6) ? s6 : s7;
    int f = fq * 8 + q;                      // feature this lane writes
    float self = yS[(size_t)node * D + f];
    float inv = 1.0f / fmaxf((float)deg, 1.0f);
    float acc = self + sv * inv;
    if (relu) acc = fmaxf(acc, 0.f);
    out[(size_t)node * D + f] = acc;
}

extern "C" void kernel_launch(void* const* d_in, const int* in_sizes, int n_in,
                              void* d_out, int out_size, void* d_ws, size_t ws_size,
                              hipStream_t stream) {
    const float* x   = (const float*)d_in[0];
    const int*   src = (const int*)d_in[1];
    const int*   dst = (const int*)d_in[2];
    const float* Ws0 = (const float*)d_in[3];
    const float* Wn0 = (const float*)d_in[4];
    const float* b0  = (const float*)d_in[5];
    const float* Ws1 = (const float*)d_in[6];
    const float* Wn1 = (const float*)d_in[7];
    const float* b1  = (const float*)d_in[8];
    float* out = (float*)d_out;

    // workspace layout
    char* p = (char*)d_ws;
    float*          yS  = (float*)p;          p += (size_t)N_NODES * D * sizeof(float);
    unsigned short* yN  = (unsigned short*)p; p += (size_t)N_NODES * D * sizeof(unsigned short);
    int* cnt = (int*)p;                       p += (size_t)N_NODES * sizeof(int);
    int* csr = (int*)p;                       p += (size_t)N_NODES * BCAP * sizeof(int);

    const int aggBlocks = (N_NODES + 3) / 4;     // 12500: wave per node, exact

    // tiny cnt zero (200 KB), stream-ordered before the fused stage
    hipMemsetAsync(cnt, 0, (size_t)N_NODES * sizeof(int), stream);

    // stage 1: layer-0 transform ∥ CSR fill (independent, co-scheduled)
    k_pre<<<2048, 256, 0, stream>>>(x, Ws0, Wn0, b0, yS, yN, src, dst, cnt, csr);

    // layer 0 aggregate -> h in d_out
    k_aggf<<<aggBlocks, 256, 0, stream>>>((const char*)yN, yS, cnt, csr, out, 1);

    // layer 1 transform + aggregate -> d_out
    k_xform<<<1024, 256, 0, stream>>>(out, Ws1, Wn1, b1, yS, yN);
    k_aggf<<<aggBlocks, 256, 0, stream>>>((const char*)yN, yS, cnt, csr, out, 0);
}